// Round 12
// baseline (1780.383 us; speedup 1.0000x reference)
//
#include <hip/hip_runtime.h>
#include <stdint.h>
#include <math.h>

#define B_SZ 1024
#define NV   4096
#define NH   4096
#define NSGN 2048

typedef short bf16x8 __attribute__((ext_vector_type(8)));
typedef short bf16x4 __attribute__((ext_vector_type(4)));
typedef float f32x4  __attribute__((ext_vector_type(4)));
typedef _Float16 f16x8 __attribute__((ext_vector_type(8)));

#define F16_ONE  ((short)0x3C00)
#define F16_NEG1 ((short)0xBC00)

// ---------------- threefry2x32 (JAX-compatible, 20 rounds) ----------------
__host__ __device__ __forceinline__ void tf2x32(uint32_t k0, uint32_t k1,
                                                uint32_t x0, uint32_t x1,
                                                uint32_t& o0, uint32_t& o1)
{
    uint32_t k2 = k0 ^ k1 ^ 0x1BD11BDAu;
#define TFR(r) { x0 += x1; x1 = (x1 << (r)) | (x1 >> (32 - (r))); x1 ^= x0; }
    x0 += k0; x1 += k1;
    TFR(13) TFR(15) TFR(26) TFR(6)
    x0 += k1; x1 += k2 + 1u;
    TFR(17) TFR(29) TFR(16) TFR(24)
    x0 += k2; x1 += k0 + 2u;
    TFR(13) TFR(15) TFR(26) TFR(6)
    x0 += k0; x1 += k1 + 3u;
    TFR(17) TFR(29) TFR(16) TFR(24)
    x0 += k1; x1 += k2 + 4u;
    TFR(13) TFR(15) TFR(26) TFR(6)
    x0 += k2; x1 += k0 + 5u;
#undef TFR
    o0 = x0; o1 = x1;
}

__device__ __forceinline__ float tf_uniform01(uint32_t k0, uint32_t k1, uint32_t idx)
{
    uint32_t a, b;
    tf2x32(k0, k1, 0u, idx, a, b);
    uint32_t bits = a ^ b;
    uint32_t fb = (bits >> 9) | 0x3F800000u;
    return __uint_as_float(fb) - 1.0f;
}

__device__ __forceinline__ float sigmoidf_(float x)
{
    if (x >= 0.0f) { float e = expf(-x); return 1.0f / (1.0f + e); }
    float e = expf(x); return e / (1.0f + e);
}

__device__ __forceinline__ void gl16(const void* g, void* l)
{
    __builtin_amdgcn_global_load_lds((const __attribute__((address_space(1))) void*)g,
                                     (__attribute__((address_space(3))) void*)l, 16, 0, 0);
}

// unpack one byte of 0/1 bits -> 8 fp16 (0 or 1.0)
__device__ __forceinline__ f16x8 unpack8(unsigned int b)
{
    short h[8];
#pragma unroll
    for (int j = 0; j < 8; ++j) h[j] = ((b >> j) & 1u) ? F16_ONE : (short)0;
    return *(f16x8*)h;
}

// ---------------- weight precompute: fp32 -> fp16 direct + transposed ----------------
__global__ __launch_bounds__(256) void conv_tr(const float* __restrict__ W,
                                               short* __restrict__ Wf,
                                               short* __restrict__ Wt)
{
    __shared__ short t[64][65];
    const int bx = blockIdx.x * 64;
    const int by = blockIdx.y * 64;
    const int r0 = threadIdx.x >> 4;
    const int c0 = (threadIdx.x & 15) * 4;
#pragma unroll
    for (int i = 0; i < 4; ++i) {
        int row = by + r0 + i * 16;
        f32x4 v = *(const f32x4*)(W + (size_t)row * 4096 + bx + c0);
        short h[4];
#pragma unroll
        for (int j = 0; j < 4; ++j) {
            union { _Float16 f; short s; } u;
            u.f = (_Float16)v[j];
            h[j] = u.s;
        }
        *(bf16x4*)(Wf + (size_t)row * 4096 + bx + c0) = *(bf16x4*)h;
#pragma unroll
        for (int j = 0; j < 4; ++j) t[c0 + j][r0 + i * 16] = h[j];
    }
    __syncthreads();
#pragma unroll
    for (int i = 0; i < 4; ++i) {
        int orow = r0 + i * 16;
        short o[4] = { t[orow][c0], t[orow][c0 + 1], t[orow][c0 + 2], t[orow][c0 + 3] };
        *(bf16x4*)(Wt + (size_t)(bx + orow) * 4096 + by + c0) = *(bf16x4*)o;
    }
}

// =====================================================================
// Fused fp16 bt-GEMM + sampling, BIT-PACKED A with cooperative unpack.
// Tile 64(M) x 128(N), BK=64, 512 thr = 8 waves (2M x 4N of 32x32).
// Per step: each thread loads 1 byte of A-bits (L2-resident), unpacks to
// one f16x8 fragment, ds_write_b128 into fragment-order As dbuf; B staged
// via gl16 (2/wave). Compute = 4+4 ds_read_b128 + 8 MFMA. LDS 48 KB.
//  MODE 0: K=4096 (A0B,B0).  MODE 1: K=8192 concat (then A1B,B1).
//  EPI 0: bern -> O0.  EPI 1: dual write O0,O1.  OB: bit-pack out.
// Grid 512 (16 bm x 32 bn), XCD-swizzled (B slice = 4 MB per XCD L2).
// =====================================================================
template<int EPI, int MODE>
__global__ __launch_bounds__(512, 4) void mm_fast(
    const ushort* __restrict__ A0B, const ushort* __restrict__ A1B,
    const short* __restrict__ B0, const short* __restrict__ B1,
    const float* __restrict__ bias,
    short* __restrict__ O0, short* __restrict__ O1,
    ushort* __restrict__ OB,
    uint32_t rk0, uint32_t rk1)
{
    __shared__ __align__(1024) short As[2][8 * 512];    // 8 KB x2
    __shared__ __align__(1024) short Bs[2][16 * 512];   // 16 KB x2

    const int bid = blockIdx.x;
    const int xcd = bid & 7, slot = bid >> 3;
    const int bn = (xcd * 4 + (slot & 3)) * 128;
    const int bm = (slot >> 2) * 64;

    const int tid = threadIdx.x;
    const int wv = tid >> 6, lane = tid & 63;
    const int l15 = lane & 15, l4 = lane >> 4;
    const int fr = l15, fc = l4 * 8;
    const int wm = wv >> 2, wn = wv & 3;

    // A-unpack mapping: thread -> subtile (tid>>6), row, byte-in-window
    const int a_sub = tid >> 6;               // 0..7 = kc*4 + msub
    const int a_row = (a_sub & 3) * 16 + l15; // 0..63
    const int a_bo  = (a_sub >> 2) * 4 + l4;  // 0..7 byte of 64-k window

    f32x4 acc[2][2] = {};
    unsigned int abyte = 0;

    const int NT = (MODE == 1) ? 128 : 64;

    auto loadA = [&](int t) {
        const unsigned char* AB = (const unsigned char*)((MODE == 1 && t >= 64) ? A1B : A0B);
        abyte = AB[(size_t)(bm + a_row) * 512 + (t & 63) * 8 + a_bo];
    };
    auto writeA = [&](int buf) {
        *(f16x8*)&As[buf][tid * 8] = unpack8(abyte);
    };
    auto stageB = [&](int buf, int t) {
        const short* B = (MODE == 1 && t >= 64) ? B1 : B0;
        const int kk = (t & 63) * 64;
        const short* brow = B + (size_t)(bn + wv * 16 + fr) * 4096 + kk + fc;
        gl16(brow,      &Bs[buf][wv * 512]);
        gl16(brow + 32, &Bs[buf][(wv + 8) * 512]);
    };
    auto compute = [&](int buf) {
        f16x8 af[2][2], bfr[2][2];
#pragma unroll
        for (int kc = 0; kc < 2; ++kc)
#pragma unroll
            for (int m = 0; m < 2; ++m)
                af[m][kc] = *(f16x8*)&As[buf][(kc * 4 + wm * 2 + m) * 512 + lane * 8];
#pragma unroll
        for (int kc = 0; kc < 2; ++kc)
#pragma unroll
            for (int n = 0; n < 2; ++n)
                bfr[n][kc] = *(f16x8*)&Bs[buf][(kc * 8 + wn * 2 + n) * 512 + lane * 8];
#pragma unroll
        for (int m = 0; m < 2; ++m)
#pragma unroll
            for (int n = 0; n < 2; ++n) {
                acc[m][n] = __builtin_amdgcn_mfma_f32_16x16x32_f16(af[m][0], bfr[n][0], acc[m][n], 0, 0, 0);
                acc[m][n] = __builtin_amdgcn_mfma_f32_16x16x32_f16(af[m][1], bfr[n][1], acc[m][n], 0, 0, 0);
            }
    };

    loadA(0); stageB(0, 0); writeA(0);
    __syncthreads();
    for (int t = 0; t < NT; ++t) {
        const int cur = t & 1;
        const bool hn = (t + 1 < NT);
        if (hn) { loadA(t + 1); stageB(cur ^ 1, t + 1); }
        compute(cur);
        if (hn) writeA(cur ^ 1);
        __syncthreads();
    }

    // ---- fused sampling epilogue (+ optional bit-pack via ballot) ----
#pragma unroll
    for (int m = 0; m < 2; ++m)
#pragma unroll
        for (int n = 0; n < 2; ++n)
#pragma unroll
            for (int r = 0; r < 4; ++r) {
                int row = bm + wm * 32 + m * 16 + l4 * 4 + r;
                int col = bn + wn * 32 + n * 16 + l15;
                float val = acc[m][n][r];
                size_t e = (size_t)row * 4096 + col;
                float p = sigmoidf_(val + bias[col]);
                float u = tf_uniform01(rk0, rk1, (uint32_t)e);
                short sv = (u < p) ? F16_ONE : (short)0;
                O0[e] = sv;
                if (EPI == 1) O1[e] = sv;
                if (OB) {
                    unsigned long long bmask = __ballot(sv != 0);
                    if (l15 == 0)
                        OB[(size_t)row * 256 + (col >> 4)] = (ushort)(bmask >> (l4 * 16));
                }
            }
}

// =====================================================================
// Dual GEMM (Gibbs interior): C = h1c @ [W2^T ; W1], N=8192 via 64 panels.
// Same cooperative bit-A unpack. Panels 0..31 -> h2 bern (kb); panels
// 32..63 -> pv sign sampling (kc) into vneg. Writes fp16 + bits.
// Grid 1024 (16 bm x 64 panels), LDS 48 KB.
// =====================================================================
__global__ __launch_bounds__(512, 4) void mm_dual(
    const ushort* __restrict__ AB,     // h1c bits
    const short* __restrict__ B2,      // W2f
    const short* __restrict__ B1T,     // W1T
    const float* __restrict__ b_h2,
    const float* __restrict__ b_v,
    const float* __restrict__ occ,
    short* __restrict__ h2n,
    short* __restrict__ vneg,
    ushort* __restrict__ h2nB,
    ushort* __restrict__ vnegB,
    uint32_t kb0, uint32_t kb1, uint32_t kc0, uint32_t kc1)
{
    __shared__ __align__(1024) short As[2][8 * 512];
    __shared__ __align__(1024) short Bs[2][16 * 512];

    const int bid = blockIdx.x;
    const int xcd = bid & 7, slot = bid >> 3;        // slot 0..127
    const int pn = xcd * 8 + (slot & 7);             // panel 0..63
    const int bm = (slot >> 3) * 64;                 // 16 bm tiles
    const bool h2half = (pn < 32);
    const short* B = h2half ? (B2  + (size_t)pn * 128 * 4096)
                            : (B1T + (size_t)(pn - 32) * 128 * 4096);

    const int tid = threadIdx.x;
    const int wv = tid >> 6, lane = tid & 63;
    const int l15 = lane & 15, l4 = lane >> 4;
    const int fr = l15, fc = l4 * 8;
    const int wm = wv >> 2, wn = wv & 3;

    const int a_sub = tid >> 6;
    const int a_row = (a_sub & 3) * 16 + l15;
    const int a_bo  = (a_sub >> 2) * 4 + l4;

    f32x4 acc[2][2] = {};
    unsigned int abyte = 0;

    auto loadA = [&](int t) {
        abyte = ((const unsigned char*)AB)[(size_t)(bm + a_row) * 512 + t * 8 + a_bo];
    };
    auto writeA = [&](int buf) {
        *(f16x8*)&As[buf][tid * 8] = unpack8(abyte);
    };
    auto stageB = [&](int buf, int t) {
        const int kk = t * 64;
        const short* brow = B + (size_t)(wv * 16 + fr) * 4096 + kk + fc;
        gl16(brow,      &Bs[buf][wv * 512]);
        gl16(brow + 32, &Bs[buf][(wv + 8) * 512]);
    };
    auto compute = [&](int buf) {
        f16x8 af[2][2], bfr[2][2];
#pragma unroll
        for (int kc = 0; kc < 2; ++kc)
#pragma unroll
            for (int m = 0; m < 2; ++m)
                af[m][kc] = *(f16x8*)&As[buf][(kc * 4 + wm * 2 + m) * 512 + lane * 8];
#pragma unroll
        for (int kc = 0; kc < 2; ++kc)
#pragma unroll
            for (int n = 0; n < 2; ++n)
                bfr[n][kc] = *(f16x8*)&Bs[buf][(kc * 8 + wn * 2 + n) * 512 + lane * 8];
#pragma unroll
        for (int m = 0; m < 2; ++m)
#pragma unroll
            for (int n = 0; n < 2; ++n) {
                acc[m][n] = __builtin_amdgcn_mfma_f32_16x16x32_f16(af[m][0], bfr[n][0], acc[m][n], 0, 0, 0);
                acc[m][n] = __builtin_amdgcn_mfma_f32_16x16x32_f16(af[m][1], bfr[n][1], acc[m][n], 0, 0, 0);
            }
    };

    loadA(0); stageB(0, 0); writeA(0);
    __syncthreads();
    for (int t = 0; t < 64; ++t) {
        const int cur = t & 1;
        const bool hn = (t + 1 < 64);
        if (hn) { loadA(t + 1); stageB(cur ^ 1, t + 1); }
        compute(cur);
        if (hn) writeA(cur ^ 1);
        __syncthreads();
    }

    // ---- epilogue: region-dependent sampling, fp16 + bits ----
#pragma unroll
    for (int m = 0; m < 2; ++m)
#pragma unroll
        for (int n = 0; n < 2; ++n)
#pragma unroll
            for (int r = 0; r < 4; ++r) {
                int row = bm + wm * 32 + m * 16 + l4 * 4 + r;
                int cl  = pn * 128 + wn * 32 + n * 16 + l15;   // 0..8191
                float val = acc[m][n][r];
                short sv;
                if (h2half) {
                    size_t e = (size_t)row * 4096 + cl;
                    float p = sigmoidf_(val + b_h2[cl]);
                    float u = tf_uniform01(kb0, kb1, (uint32_t)e);
                    sv = (u < p) ? F16_ONE : (short)0;
                    h2n[e] = sv;
                    unsigned long long bmask = __ballot(sv != 0);
                    if (l15 == 0)
                        h2nB[(size_t)row * 256 + (cl >> 4)] = (ushort)(bmask >> (l4 * 16));
                } else {
                    int vcol = cl - 4096;
                    if (vcol & 1) {
                        int s = (vcol - 1) >> 1;
                        uint32_t e = (uint32_t)(row * 2048 + s);
                        float p = sigmoidf_(val + b_v[vcol]);
                        float u = tf_uniform01(kc0, kc1, e);
                        sv = (u < p) ? F16_ONE : (short)0;
                    } else {
                        sv = (occ[(size_t)row * 2048 + (vcol >> 1)] != 0.0f) ? F16_ONE : (short)0;
                    }
                    vneg[(size_t)row * 4096 + vcol] = sv;
                    unsigned long long bmask = __ballot(sv != 0);
                    if (l15 == 0)
                        vnegB[(size_t)row * 256 + (vcol >> 4)] = (ushort)(bmask >> (l4 * 16));
                }
            }
}

// =====================================================================
// Gradient GEMM (exact): Out[i,j] = (sum_b Xn Yn - Xp Yp)/1024, fp16 states.
// tile 128x128, 256 threads = 4 waves (64x64 each); unchanged.
// =====================================================================
template<int W1MODE>
__global__ __launch_bounds__(256) void grad_mm(
    const short* __restrict__ Xn, const short* __restrict__ Yn,
    const short* __restrict__ Xp, const short* __restrict__ Yp_bf,
    const float* __restrict__ Yp_f32,
    float* __restrict__ Out)
{
    __shared__ __align__(1024) short Xs[2][8 * 512];
    __shared__ __align__(1024) short Ys[2][8 * 512];

    const int tid = threadIdx.x;
    const int bi = blockIdx.y * 128, bj = blockIdx.x * 128;
    const int wv = tid >> 6, lane = tid & 63;
    const int wr = (wv >> 1) * 64, wc = (wv & 1) * 64;
    const int l15 = lane & 15, l4 = lane >> 4;

    const int cg = (tid & 31) * 4;
    const int kg = tid >> 5;
    const int qsub = (tid & 31) >> 2;
    const int koff = (kg >> 1) * 128 + (kg & 1) * 4;

    f32x4 acc[4][4] = {};
    short xr[4][4];
    short yr[4][4];

    auto loadT = [&](int bt) {
        const bool neg = bt < 32;
        const int b0 = (bt & 31) * 32;
        const short* X = neg ? Xn : Xp;
#pragma unroll
        for (int i = 0; i < 4; ++i)
            *(bf16x4*)xr[i] = *(const bf16x4*)(X + (size_t)(b0 + kg * 4 + i) * NH + bi + cg);
        if (W1MODE) {
            if (neg) {
#pragma unroll
                for (int i = 0; i < 4; ++i) {
                    bf16x8 v = *(const bf16x8*)(Yn + (size_t)(b0 + kg * 4 + i) * NV + 2 * (bj + cg));
                    yr[i][0] = v[1]; yr[i][1] = v[3]; yr[i][2] = v[5]; yr[i][3] = v[7];
                }
            } else {
#pragma unroll
                for (int i = 0; i < 4; ++i) {
                    const float* p = Yp_f32 + (size_t)(b0 + kg * 4 + i) * NV + 2 * (bj + cg);
                    f32x4 a = *(const f32x4*)p;
                    f32x4 b = *(const f32x4*)(p + 4);
                    yr[i][0] = (a[1] != 0.0f) ? F16_NEG1 : (short)0;
                    yr[i][1] = (a[3] != 0.0f) ? F16_NEG1 : (short)0;
                    yr[i][2] = (b[1] != 0.0f) ? F16_NEG1 : (short)0;
                    yr[i][3] = (b[3] != 0.0f) ? F16_NEG1 : (short)0;
                }
            }
        } else {
            const short* Y = neg ? Yn : Yp_bf;
            const short sx = neg ? (short)0 : (short)0x8000;
#pragma unroll
            for (int i = 0; i < 4; ++i) {
                bf16x4 v = *(const bf16x4*)(Y + (size_t)(b0 + kg * 4 + i) * NH + bj + cg);
#pragma unroll
                for (int j = 0; j < 4; ++j) yr[i][j] = (short)(v[j] ^ sx);
            }
        }
    };
    auto writeT = [&](int buf) {
#pragma unroll
        for (int j = 0; j < 4; ++j) {
            int r = (tid & 3) * 4 + j;
            int off = qsub * 512 + koff + ((r ^ qsub) & 15) * 8;
            short wx[4] = {xr[0][j], xr[1][j], xr[2][j], xr[3][j]};
            short wy[4] = {yr[0][j], yr[1][j], yr[2][j], yr[3][j]};
            *(bf16x4*)&Xs[buf][off] = *(bf16x4*)wx;
            *(bf16x4*)&Ys[buf][off] = *(bf16x4*)wy;
        }
    };

    loadT(0);
    writeT(0);
    __syncthreads();

    for (int bt = 0; bt < 64; ++bt) {
        const int cur = bt & 1;
        if (bt + 1 < 64) loadT(bt + 1);

        f16x8 xf[4], yf[4];
#pragma unroll
        for (int m = 0; m < 4; ++m) {
            int sm = (wv >> 1) * 4 + m;
            xf[m] = *(f16x8*)&Xs[cur][sm * 512 + l4 * 128 + ((l15 ^ sm) & 15) * 8];
        }
#pragma unroll
        for (int n = 0; n < 4; ++n) {
            int sn = (wv & 1) * 4 + n;
            yf[n] = *(f16x8*)&Ys[cur][sn * 512 + l4 * 128 + ((l15 ^ sn) & 15) * 8];
        }
#pragma unroll
        for (int m = 0; m < 4; ++m)
#pragma unroll
            for (int n = 0; n < 4; ++n)
                acc[m][n] = __builtin_amdgcn_mfma_f32_16x16x32_f16(xf[m], yf[n], acc[m][n], 0, 0, 0);

        if (bt + 1 < 64) writeT(cur ^ 1);
        __syncthreads();
    }

    const float invB = 1.0f / 1024.0f;
#pragma unroll
    for (int m = 0; m < 4; ++m)
#pragma unroll
        for (int n = 0; n < 4; ++n)
#pragma unroll
            for (int r = 0; r < 4; ++r) {
                int i_ = bi + wr + m * 16 + l4 * 4 + r;
                int j_ = bj + wc + n * 16 + l15;
                if (W1MODE) {
                    Out[(size_t)i_ * NV + 2 * j_ + 1] = acc[m][n][r] * invB;
                    Out[(size_t)i_ * NV + 2 * j_]     = 0.0f;
                } else {
                    Out[(size_t)i_ * NH + j_] = acc[m][n][r] * invB;
                }
            }
}

// ---------------- small kernels ----------------
__global__ void cvt_kernel(const float* __restrict__ in, short* __restrict__ out,
                           ushort* __restrict__ outB, int n)
{
    int e = blockIdx.x * 256 + threadIdx.x;
    short v = (e < n && in[e] != 0.0f) ? F16_ONE : (short)0;
    if (e < n) out[e] = v;
    unsigned long long m = __ballot(v != 0);
    int lane = threadIdx.x & 63;
    if ((lane & 15) == 0 && e < n) {
        int e0 = e - lane;
        outB[(e0 >> 4) + (lane >> 4)] = (ushort)(m >> (lane & 48));
    }
}

__global__ void dbv_fast(const float* __restrict__ vdata, const short* __restrict__ vneg,
                         float* __restrict__ out)
{
    __shared__ float part[4][64];
    int c = threadIdx.x & 63, rg = threadIdx.x >> 6;
    int s = blockIdx.x * 64 + c;
    float acc = 0.0f;
    for (int b = rg; b < B_SZ; b += 4)
        acc += ((vneg[(size_t)b * NV + 2 * s + 1] != 0) ? 1.0f : 0.0f)
             - vdata[(size_t)b * NV + 2 * s + 1];
    part[rg][c] = acc;
    __syncthreads();
    if (rg == 0) {
        out[2 * s + 1] = (part[0][c] + part[1][c] + part[2][c] + part[3][c]) * (1.0f / 1024.0f);
        out[2 * s] = 0.0f;
    }
}

__global__ void dbh_fast(const short* __restrict__ Xp, const short* __restrict__ Xn,
                         float* __restrict__ out)
{
    __shared__ int part[4][64];
    int c = threadIdx.x & 63, rg = threadIdx.x >> 6;
    int j = blockIdx.x * 64 + c;
    int acc = 0;
    for (int b = rg; b < B_SZ; b += 4)
        acc += (int)(Xn[(size_t)b * NH + j] != 0) - (int)(Xp[(size_t)b * NH + j] != 0);
    part[rg][c] = acc;
    __syncthreads();
    if (rg == 0)
        out[j] = (float)(part[0][c] + part[1][c] + part[2][c] + part[3][c]) * (1.0f / 1024.0f);
}

__global__ void zero_kernel(unsigned* p) { *p = 0u; }

__global__ void loss_count2(const float* __restrict__ vdata,
                            const short* __restrict__ vneg, unsigned* cnt)
{
    __shared__ int part[4];
    int t = blockIdx.x * 256 + threadIdx.x;
    int local = 0;
#pragma unroll
    for (int it = 0; it < 8; ++it) {
        int e = t + it * 262144;
        int b = e >> 11, s = e & 2047;
        float st = vdata[(size_t)b * NV + 2 * s + 1];
        float sp = (vneg[(size_t)b * NV + 2 * s + 1] != 0) ? 1.0f : 0.0f;
        local += (st != sp) ? 1 : 0;
    }
#pragma unroll
    for (int off = 32; off; off >>= 1) local += __shfl_down(local, off, 64);
    if ((threadIdx.x & 63) == 0) part[threadIdx.x >> 6] = local;
    __syncthreads();
    if (threadIdx.x == 0)
        atomicAdd(cnt, (unsigned)(part[0] + part[1] + part[2] + part[3]));
}

__global__ void loss_final_kernel(const unsigned* cnt, float* out, float lp, float lm)
{
    float mis = (float)(*cnt);
    float mat = 2097152.0f - mis;
    out[0] = -((mat * lp + mis * lm) * (1.0f / 2097152.0f));
}

// ---------------- host ----------------
extern "C" void kernel_launch(void* const* d_in, const int* in_sizes, int n_in,
                              void* d_out, int out_size, void* d_ws, size_t ws_size,
                              hipStream_t stream)
{
    (void)in_sizes; (void)n_in; (void)out_size; (void)ws_size;
    const float* v_data = (const float*)d_in[0];
    const float* occ    = (const float*)d_in[1];
    const float* W1     = (const float*)d_in[2];
    const float* b_v    = (const float*)d_in[3];
    const float* b_h1   = (const float*)d_in[4];
    const float* W2     = (const float*)d_in[5];
    const float* b_h2   = (const float*)d_in[6];
    float* out = (float*)d_out;

    char* w = (char*)d_ws;
    short* vneg = (short*)w;
    short* h1d  = vneg + (size_t)B_SZ * NV;
    short* h2d  = h1d  + (size_t)B_SZ * NH;
    short* h1c  = h2d  + (size_t)B_SZ * NH;
    short* h2n  = h1c  + (size_t)B_SZ * NH;
    ushort* vnegB = (ushort*)(h2n + (size_t)B_SZ * NH);   // 512 KB each
    ushort* h2nB  = vnegB + (size_t)B_SZ * 256;
    ushort* h1cB  = h2nB  + (size_t)B_SZ * 256;
    ushort* h1dB  = h1cB  + (size_t)B_SZ * 256;
    unsigned* cnt = (unsigned*)(h1dB + (size_t)B_SZ * 256);

    // d_out doubles as fp16 weight scratch (128 MB of the 134 MB output;
    // fully overwritten by gradient kernels afterwards).
    short* W1f = (short*)(((uintptr_t)(out + 1) + 15) & ~(uintptr_t)15);
    short* W1T = W1f + (size_t)NH * NV;
    short* W2f = W1T + (size_t)NH * NV;
    short* W2T = W2f + (size_t)NH * NH;

    // ---- JAX key derivation ----
    const uint32_t r0 = 0u, r1 = 42u;
    uint32_t kp1a, kp1b, kp2a, kp2b, kfa, kfb, kla, klb;
    tf2x32(r0, r1, 0u, 0u, kp1a, kp1b);
    tf2x32(r0, r1, 0u, 1u, kp2a, kp2b);
    tf2x32(r0, r1, 0u, 2u, kfa, kfb);
    tf2x32(r0, r1, 0u, 3u, kla, klb);
    uint32_t kaA[2], kaB[2], kbA[2], kbB[2], kcA[2], kcB[2];
    for (int i = 0; i < 2; ++i) {
        uint32_t fa, fb;
        tf2x32(kla, klb, 0u, (uint32_t)i, fa, fb);
        tf2x32(fa, fb, 0u, 0u, kaA[i], kaB[i]);
        tf2x32(fa, fb, 0u, 1u, kbA[i], kbB[i]);
        tf2x32(fa, fb, 0u, 2u, kcA[i], kcB[i]);
    }

    const int T = 256;
    const int NELEM = B_SZ * NH;
    dim3 gMM(512);
    dim3 gTr(64, 64);

    conv_tr<<<gTr, 256, 0, stream>>>(W1, W1f, W1T);
    conv_tr<<<gTr, 256, 0, stream>>>(W2, W2f, W2T);

    cvt_kernel<<<NELEM / T, T, 0, stream>>>(v_data, vneg, vnegB, NELEM);

    // positive phase (bit-A everywhere; emit bits for downstream)
    mm_fast<0, 0><<<gMM, 512, 0, stream>>>(vnegB, nullptr, W1f, nullptr,
                                           b_h1, h1d, nullptr, h1dB, kp1a, kp1b);
    mm_fast<1, 0><<<gMM, 512, 0, stream>>>(h1dB, nullptr, W2f, nullptr,
                                           b_h2, h2d, h2n, h2nB, kp2a, kp2b);

    // Gibbs loop (k = 2): h1 update (K=8192 concat), then fused dual
    for (int i = 0; i < 2; ++i) {
        mm_fast<0, 1><<<gMM, 512, 0, stream>>>(vnegB, h2nB, W1f, W2T,
                                               b_h1, h1c, nullptr, h1cB, kaA[i], kaB[i]);
        mm_dual<<<1024, 512, 0, stream>>>(h1cB, W2f, W1T, b_h2, b_v, occ,
                                          h2n, vneg, h2nB, vnegB,
                                          kbA[i], kbB[i], kcA[i], kcB[i]);
    }

    // final hidden refresh (h1c feeds grads only -> no bits out)
    mm_fast<0, 1><<<gMM, 512, 0, stream>>>(vnegB, h2nB, W1f, W2T,
                                           b_h1, h1c, nullptr, nullptr, kfa, kfb);

    // outputs (weight scratch dead after this point)
    float* dW1o  = out + 1;
    float* dbvo  = dW1o + (size_t)NH * NV;
    float* dbh1o = dbvo + NV;
    float* dW2o  = dbh1o + NH;
    float* dbh2o = dW2o + (size_t)NH * NH;

    grad_mm<1><<<dim3(NSGN / 128, NH / 128), T, 0, stream>>>(h1c, vneg, h1d, (short*)nullptr, v_data, dW1o);
    grad_mm<0><<<dim3(NH / 128, NH / 128), T, 0, stream>>>(h1c, h2n, h1d, h2d, (const float*)nullptr, dW2o);
    dbv_fast<<<NSGN / 64, T, 0, stream>>>(v_data, vneg, dbvo);
    dbh_fast<<<NH / 64, T, 0, stream>>>(h1d, h1c, dbh1o);
    dbh_fast<<<NH / 64, T, 0, stream>>>(h2d, h2n, dbh2o);

    zero_kernel<<<1, 1, 0, stream>>>(cnt);
    loss_count2<<<1024, T, 0, stream>>>(v_data, vneg, cnt);
    loss_final_kernel<<<1, 1, 0, stream>>>(cnt, out, logf(1.0f + 1e-7f), logf(1e-7f));
}

// Round 13
// 1448.805 us; speedup vs baseline: 1.2289x; 1.2289x over previous
//
#include <hip/hip_runtime.h>
#include <stdint.h>
#include <math.h>

#define B_SZ 1024
#define NV   4096
#define NH   4096
#define NSGN 2048

typedef short bf16x8 __attribute__((ext_vector_type(8)));
typedef short bf16x4 __attribute__((ext_vector_type(4)));
typedef float f32x4  __attribute__((ext_vector_type(4)));
typedef _Float16 f16x8 __attribute__((ext_vector_type(8)));

#define F16_ONE  ((short)0x3C00)
#define F16_NEG1 ((short)0xBC00)

// ---------------- threefry2x32 (JAX-compatible, 20 rounds) ----------------
__host__ __device__ __forceinline__ void tf2x32(uint32_t k0, uint32_t k1,
                                                uint32_t x0, uint32_t x1,
                                                uint32_t& o0, uint32_t& o1)
{
    uint32_t k2 = k0 ^ k1 ^ 0x1BD11BDAu;
#define TFR(r) { x0 += x1; x1 = (x1 << (r)) | (x1 >> (32 - (r))); x1 ^= x0; }
    x0 += k0; x1 += k1;
    TFR(13) TFR(15) TFR(26) TFR(6)
    x0 += k1; x1 += k2 + 1u;
    TFR(17) TFR(29) TFR(16) TFR(24)
    x0 += k2; x1 += k0 + 2u;
    TFR(13) TFR(15) TFR(26) TFR(6)
    x0 += k0; x1 += k1 + 3u;
    TFR(17) TFR(29) TFR(16) TFR(24)
    x0 += k1; x1 += k2 + 4u;
    TFR(13) TFR(15) TFR(26) TFR(6)
    x0 += k2; x1 += k0 + 5u;
#undef TFR
    o0 = x0; o1 = x1;
}

__device__ __forceinline__ float tf_uniform01(uint32_t k0, uint32_t k1, uint32_t idx)
{
    uint32_t a, b;
    tf2x32(k0, k1, 0u, idx, a, b);
    uint32_t bits = a ^ b;
    uint32_t fb = (bits >> 9) | 0x3F800000u;
    return __uint_as_float(fb) - 1.0f;
}

__device__ __forceinline__ float sigmoidf_(float x)
{
    if (x >= 0.0f) { float e = expf(-x); return 1.0f / (1.0f + e); }
    float e = expf(x); return e / (1.0f + e);
}

__device__ __forceinline__ void gl16(const void* g, void* l)
{
    __builtin_amdgcn_global_load_lds((const __attribute__((address_space(1))) void*)g,
                                     (__attribute__((address_space(3))) void*)l, 16, 0, 0);
}

// ---------------- weight precompute: fp32 -> fp16 direct + transposed ----------------
__global__ __launch_bounds__(256) void conv_tr(const float* __restrict__ W,
                                               short* __restrict__ Wf,
                                               short* __restrict__ Wt)
{
    __shared__ short t[64][65];
    const int bx = blockIdx.x * 64;
    const int by = blockIdx.y * 64;
    const int r0 = threadIdx.x >> 4;
    const int c0 = (threadIdx.x & 15) * 4;
#pragma unroll
    for (int i = 0; i < 4; ++i) {
        int row = by + r0 + i * 16;
        f32x4 v = *(const f32x4*)(W + (size_t)row * 4096 + bx + c0);
        short h[4];
#pragma unroll
        for (int j = 0; j < 4; ++j) {
            union { _Float16 f; short s; } u;
            u.f = (_Float16)v[j];
            h[j] = u.s;
        }
        *(bf16x4*)(Wf + (size_t)row * 4096 + bx + c0) = *(bf16x4*)h;
#pragma unroll
        for (int j = 0; j < 4; ++j) t[c0 + j][r0 + i * 16] = h[j];
    }
    __syncthreads();
#pragma unroll
    for (int i = 0; i < 4; ++i) {
        int orow = r0 + i * 16;
        short o[4] = { t[orow][c0], t[orow][c0 + 1], t[orow][c0 + 2], t[orow][c0 + 3] };
        *(bf16x4*)(Wt + (size_t)(bx + orow) * 4096 + by + c0) = *(bf16x4*)o;
    }
}

// =====================================================================
// m97-replica chunk GEMM: 128x128 tile, BK=32, 256 thr = 4 waves (64x64
// each, 16 MFMA/step), 32 KB LDS dbuf, 4 gl16/wave/step, 64 steps =
// K-chunk 2048. Writes f32 partials P[ck][1024][NW].
//  MODE 0: K=4096 -> 2 chunks (A0,B0). grid 512.
//  MODE 1: K=8192 concat -> 4 chunks (A0,B0 then A1,B1). grid 1024.
//  MODE 2: dual-N 8192 (64 panels: B0=W2f pn<32, B1=W1T), K=4096 ->
//          2 chunks. grid 1024.
// XCD-swizzled.
// =====================================================================
template<int MODE>
__global__ __launch_bounds__(256, 3) void mm_chunk(
    const short* __restrict__ A0, const short* __restrict__ A1,
    const short* __restrict__ B0, const short* __restrict__ B1,
    float* __restrict__ P)
{
    __shared__ __align__(1024) short As[2][8 * 512];
    __shared__ __align__(1024) short Bs[2][8 * 512];

    const int bid = blockIdx.x;
    const int xcd = bid & 7, slot = bid >> 3;

    int bm, bncol, ck, kbase, NW;
    const short* Ap;
    const short* Bp;
    if (MODE == 2) {
        int pn = xcd * 8 + (slot & 7);      // 0..63
        int rest = slot >> 3;               // 0..15
        bm = (rest & 7) * 128;
        ck = rest >> 3;                     // 0..1
        kbase = ck * 2048;
        Ap = A0;
        Bp = (pn < 32) ? (B0 + (size_t)pn * 128 * 4096)
                       : (B1 + (size_t)(pn - 32) * 128 * 4096);
        bncol = pn * 128;
        NW = 8192;
    } else {
        int pn = xcd * 4 + (slot & 3);      // 0..31
        int rest = slot >> 2;               // MODE0: 0..15, MODE1: 0..31
        bm = (rest & 7) * 128;
        ck = rest >> 3;                     // MODE0: 0..1, MODE1: 0..3
        if (MODE == 1 && ck >= 2) {
            Ap = A1; Bp = B1 + (size_t)pn * 128 * 4096; kbase = (ck - 2) * 2048;
        } else {
            Ap = A0; Bp = B0 + (size_t)pn * 128 * 4096; kbase = ck * 2048;
        }
        bncol = pn * 128;
        NW = 4096;
    }

    const int tid = threadIdx.x;
    const int wv = tid >> 6, lane = tid & 63;
    const int l15 = lane & 15, l4 = lane >> 4;
    const int fr = l15, fc = l4 * 8;

    f32x4 acc[4][4] = {};

    auto stage = [&](int buf, int t) {
        const int kk = kbase + t * 32;
#pragma unroll
        for (int c = 0; c < 2; ++c) {
            int sub = wv * 2 + c;
            gl16(Ap + (size_t)(bm + sub * 16 + fr) * 4096 + kk + fc, &As[buf][sub * 512]);
            gl16(Bp + (size_t)(sub * 16 + fr) * 4096 + kk + fc, &Bs[buf][sub * 512]);
        }
    };
    auto compute = [&](int buf) {
        f16x8 xf[4], yf[4];
#pragma unroll
        for (int m = 0; m < 4; ++m)
            xf[m] = *(f16x8*)&As[buf][((wv >> 1) * 4 + m) * 512 + lane * 8];
#pragma unroll
        for (int n = 0; n < 4; ++n)
            yf[n] = *(f16x8*)&Bs[buf][((wv & 1) * 4 + n) * 512 + lane * 8];
#pragma unroll
        for (int m = 0; m < 4; ++m)
#pragma unroll
            for (int n = 0; n < 4; ++n)
                acc[m][n] = __builtin_amdgcn_mfma_f32_16x16x32_f16(xf[m], yf[n], acc[m][n], 0, 0, 0);
    };

    stage(0, 0);
    __syncthreads();
    for (int t = 0; t < 64; ++t) {
        const int cur = t & 1;
        if (t + 1 < 64) stage(cur ^ 1, t + 1);
        compute(cur);
        __syncthreads();
    }

    float* Pc = P + (size_t)ck * 1024 * NW;
#pragma unroll
    for (int m = 0; m < 4; ++m)
#pragma unroll
        for (int n = 0; n < 4; ++n)
#pragma unroll
            for (int r = 0; r < 4; ++r) {
                int row = bm + (wv >> 1) * 64 + m * 16 + l4 * 4 + r;
                int col = bncol + (wv & 1) * 64 + n * 16 + l15;
                Pc[(size_t)row * NW + col] = acc[m][n][r];
            }
}

// ---------------- combine + sample (N=4096 logits) ----------------
template<int EPI, int NC>
__global__ __launch_bounds__(256) void combine_h(
    const float* __restrict__ P, const float* __restrict__ bias,
    short* __restrict__ O0, short* __restrict__ O1,
    uint32_t k0, uint32_t k1)
{
    size_t e0 = ((size_t)blockIdx.x * 256 + threadIdx.x) * 8;
    f32x4 s0 = {}, s1 = {};
#pragma unroll
    for (int c = 0; c < NC; ++c) {
        const float* p = P + (size_t)c * 4194304 + e0;
        s0 += *(const f32x4*)p;
        s1 += *(const f32x4*)(p + 4);
    }
    int col = (int)(e0 & 4095);
    short o[8];
#pragma unroll
    for (int j = 0; j < 8; ++j) {
        float v = ((j < 4) ? s0[j] : s1[j - 4]) + bias[col + j];
        float pr = sigmoidf_(v);
        float u = tf_uniform01(k0, k1, (uint32_t)(e0 + j));
        o[j] = (u < pr) ? F16_ONE : (short)0;
    }
    *(bf16x8*)&O0[e0] = *(bf16x8*)o;
    if (EPI == 1) *(bf16x8*)&O1[e0] = *(bf16x8*)o;
}

// ---------------- combine + sample (dual N=8192: h2 | pv-sign) ----------------
__global__ __launch_bounds__(256) void combine_dual(
    const float* __restrict__ P,
    const float* __restrict__ b_h2, const float* __restrict__ b_v,
    const float* __restrict__ occ,
    short* __restrict__ h2n, short* __restrict__ vneg,
    uint32_t kb0, uint32_t kb1, uint32_t kc0, uint32_t kc1)
{
    size_t e0 = ((size_t)blockIdx.x * 256 + threadIdx.x) * 8;
    int row = (int)(e0 >> 13);
    int cl  = (int)(e0 & 8191);
    f32x4 s0 = {}, s1 = {};
#pragma unroll
    for (int c = 0; c < 2; ++c) {
        const float* p = P + (size_t)c * 8388608 + e0;
        s0 += *(const f32x4*)p;
        s1 += *(const f32x4*)(p + 4);
    }
    short o[8];
    if (cl < 4096) {
#pragma unroll
        for (int j = 0; j < 8; ++j) {
            float v = ((j < 4) ? s0[j] : s1[j - 4]) + b_h2[cl + j];
            float pr = sigmoidf_(v);
            size_t e = (size_t)row * 4096 + cl + j;
            float u = tf_uniform01(kb0, kb1, (uint32_t)e);
            o[j] = (u < pr) ? F16_ONE : (short)0;
        }
        *(bf16x8*)&h2n[(size_t)row * 4096 + cl] = *(bf16x8*)o;
    } else {
        int v0 = cl - 4096;
#pragma unroll
        for (int j = 0; j < 8; ++j) {
            int vcol = v0 + j;
            if (vcol & 1) {
                int s = (vcol - 1) >> 1;
                float v = ((j < 4) ? s0[j] : s1[j - 4]) + b_v[vcol];
                float pr = sigmoidf_(v);
                float u = tf_uniform01(kc0, kc1, (uint32_t)(row * 2048 + s));
                o[j] = (u < pr) ? F16_ONE : (short)0;
            } else {
                o[j] = (occ[(size_t)row * 2048 + (vcol >> 1)] != 0.0f) ? F16_ONE : (short)0;
            }
        }
        *(bf16x8*)&vneg[(size_t)row * 4096 + v0] = *(bf16x8*)o;
    }
}

// =====================================================================
// Gradient GEMM (exact): Out[i,j] = (sum_b Xn Yn - Xp Yp)/1024, fp16 states.
// tile 128x128, 256 threads = 4 waves (64x64 each); unchanged.
// =====================================================================
template<int W1MODE>
__global__ __launch_bounds__(256) void grad_mm(
    const short* __restrict__ Xn, const short* __restrict__ Yn,
    const short* __restrict__ Xp, const short* __restrict__ Yp_bf,
    const float* __restrict__ Yp_f32,
    float* __restrict__ Out)
{
    __shared__ __align__(1024) short Xs[2][8 * 512];
    __shared__ __align__(1024) short Ys[2][8 * 512];

    const int tid = threadIdx.x;
    const int bi = blockIdx.y * 128, bj = blockIdx.x * 128;
    const int wv = tid >> 6, lane = tid & 63;
    const int wr = (wv >> 1) * 64, wc = (wv & 1) * 64;
    const int l15 = lane & 15, l4 = lane >> 4;

    const int cg = (tid & 31) * 4;
    const int kg = tid >> 5;
    const int qsub = (tid & 31) >> 2;
    const int koff = (kg >> 1) * 128 + (kg & 1) * 4;

    f32x4 acc[4][4] = {};
    short xr[4][4];
    short yr[4][4];

    auto loadT = [&](int bt) {
        const bool neg = bt < 32;
        const int b0 = (bt & 31) * 32;
        const short* X = neg ? Xn : Xp;
#pragma unroll
        for (int i = 0; i < 4; ++i)
            *(bf16x4*)xr[i] = *(const bf16x4*)(X + (size_t)(b0 + kg * 4 + i) * NH + bi + cg);
        if (W1MODE) {
            if (neg) {
#pragma unroll
                for (int i = 0; i < 4; ++i) {
                    bf16x8 v = *(const bf16x8*)(Yn + (size_t)(b0 + kg * 4 + i) * NV + 2 * (bj + cg));
                    yr[i][0] = v[1]; yr[i][1] = v[3]; yr[i][2] = v[5]; yr[i][3] = v[7];
                }
            } else {
#pragma unroll
                for (int i = 0; i < 4; ++i) {
                    const float* p = Yp_f32 + (size_t)(b0 + kg * 4 + i) * NV + 2 * (bj + cg);
                    f32x4 a = *(const f32x4*)p;
                    f32x4 b = *(const f32x4*)(p + 4);
                    yr[i][0] = (a[1] != 0.0f) ? F16_NEG1 : (short)0;
                    yr[i][1] = (a[3] != 0.0f) ? F16_NEG1 : (short)0;
                    yr[i][2] = (b[1] != 0.0f) ? F16_NEG1 : (short)0;
                    yr[i][3] = (b[3] != 0.0f) ? F16_NEG1 : (short)0;
                }
            }
        } else {
            const short* Y = neg ? Yn : Yp_bf;
            const short sx = neg ? (short)0 : (short)0x8000;
#pragma unroll
            for (int i = 0; i < 4; ++i) {
                bf16x4 v = *(const bf16x4*)(Y + (size_t)(b0 + kg * 4 + i) * NH + bj + cg);
#pragma unroll
                for (int j = 0; j < 4; ++j) yr[i][j] = (short)(v[j] ^ sx);
            }
        }
    };
    auto writeT = [&](int buf) {
#pragma unroll
        for (int j = 0; j < 4; ++j) {
            int r = (tid & 3) * 4 + j;
            int off = qsub * 512 + koff + ((r ^ qsub) & 15) * 8;
            short wx[4] = {xr[0][j], xr[1][j], xr[2][j], xr[3][j]};
            short wy[4] = {yr[0][j], yr[1][j], yr[2][j], yr[3][j]};
            *(bf16x4*)&Xs[buf][off] = *(bf16x4*)wx;
            *(bf16x4*)&Ys[buf][off] = *(bf16x4*)wy;
        }
    };

    loadT(0);
    writeT(0);
    __syncthreads();

    for (int bt = 0; bt < 64; ++bt) {
        const int cur = bt & 1;
        if (bt + 1 < 64) loadT(bt + 1);

        f16x8 xf[4], yf[4];
#pragma unroll
        for (int m = 0; m < 4; ++m) {
            int sm = (wv >> 1) * 4 + m;
            xf[m] = *(f16x8*)&Xs[cur][sm * 512 + l4 * 128 + ((l15 ^ sm) & 15) * 8];
        }
#pragma unroll
        for (int n = 0; n < 4; ++n) {
            int sn = (wv & 1) * 4 + n;
            yf[n] = *(f16x8*)&Ys[cur][sn * 512 + l4 * 128 + ((l15 ^ sn) & 15) * 8];
        }
#pragma unroll
        for (int m = 0; m < 4; ++m)
#pragma unroll
            for (int n = 0; n < 4; ++n)
                acc[m][n] = __builtin_amdgcn_mfma_f32_16x16x32_f16(xf[m], yf[n], acc[m][n], 0, 0, 0);

        if (bt + 1 < 64) writeT(cur ^ 1);
        __syncthreads();
    }

    const float invB = 1.0f / 1024.0f;
#pragma unroll
    for (int m = 0; m < 4; ++m)
#pragma unroll
        for (int n = 0; n < 4; ++n)
#pragma unroll
            for (int r = 0; r < 4; ++r) {
                int i_ = bi + wr + m * 16 + l4 * 4 + r;
                int j_ = bj + wc + n * 16 + l15;
                if (W1MODE) {
                    Out[(size_t)i_ * NV + 2 * j_ + 1] = acc[m][n][r] * invB;
                    Out[(size_t)i_ * NV + 2 * j_]     = 0.0f;
                } else {
                    Out[(size_t)i_ * NH + j_] = acc[m][n][r] * invB;
                }
            }
}

// ---------------- small kernels ----------------
__global__ void cvt_kernel(const float* __restrict__ in, short* __restrict__ out, int n)
{
    int e = blockIdx.x * 256 + threadIdx.x;
    if (e < n) out[e] = (in[e] != 0.0f) ? F16_ONE : (short)0;
}

__global__ void dbv_fast(const float* __restrict__ vdata, const short* __restrict__ vneg,
                         float* __restrict__ out)
{
    __shared__ float part[4][64];
    int c = threadIdx.x & 63, rg = threadIdx.x >> 6;
    int s = blockIdx.x * 64 + c;
    float acc = 0.0f;
    for (int b = rg; b < B_SZ; b += 4)
        acc += ((vneg[(size_t)b * NV + 2 * s + 1] != 0) ? 1.0f : 0.0f)
             - vdata[(size_t)b * NV + 2 * s + 1];
    part[rg][c] = acc;
    __syncthreads();
    if (rg == 0) {
        out[2 * s + 1] = (part[0][c] + part[1][c] + part[2][c] + part[3][c]) * (1.0f / 1024.0f);
        out[2 * s] = 0.0f;
    }
}

__global__ void dbh_fast(const short* __restrict__ Xp, const short* __restrict__ Xn,
                         float* __restrict__ out)
{
    __shared__ int part[4][64];
    int c = threadIdx.x & 63, rg = threadIdx.x >> 6;
    int j = blockIdx.x * 64 + c;
    int acc = 0;
    for (int b = rg; b < B_SZ; b += 4)
        acc += (int)(Xn[(size_t)b * NH + j] != 0) - (int)(Xp[(size_t)b * NH + j] != 0);
    part[rg][c] = acc;
    __syncthreads();
    if (rg == 0)
        out[j] = (float)(part[0][c] + part[1][c] + part[2][c] + part[3][c]) * (1.0f / 1024.0f);
}

__global__ void zero_kernel(unsigned* p) { *p = 0u; }

__global__ void loss_count2(const float* __restrict__ vdata,
                            const short* __restrict__ vneg, unsigned* cnt)
{
    __shared__ int part[4];
    int t = blockIdx.x * 256 + threadIdx.x;
    int local = 0;
#pragma unroll
    for (int it = 0; it < 8; ++it) {
        int e = t + it * 262144;
        int b = e >> 11, s = e & 2047;
        float st = vdata[(size_t)b * NV + 2 * s + 1];
        float sp = (vneg[(size_t)b * NV + 2 * s + 1] != 0) ? 1.0f : 0.0f;
        local += (st != sp) ? 1 : 0;
    }
#pragma unroll
    for (int off = 32; off; off >>= 1) local += __shfl_down(local, off, 64);
    if ((threadIdx.x & 63) == 0) part[threadIdx.x >> 6] = local;
    __syncthreads();
    if (threadIdx.x == 0)
        atomicAdd(cnt, (unsigned)(part[0] + part[1] + part[2] + part[3]));
}

__global__ void loss_final_kernel(const unsigned* cnt, float* out, float lp, float lm)
{
    float mis = (float)(*cnt);
    float mat = 2097152.0f - mis;
    out[0] = -((mat * lp + mis * lm) * (1.0f / 2097152.0f));
}

// ---------------- host ----------------
extern "C" void kernel_launch(void* const* d_in, const int* in_sizes, int n_in,
                              void* d_out, int out_size, void* d_ws, size_t ws_size,
                              hipStream_t stream)
{
    (void)in_sizes; (void)n_in; (void)out_size; (void)ws_size;
    const float* v_data = (const float*)d_in[0];
    const float* occ    = (const float*)d_in[1];
    const float* W1     = (const float*)d_in[2];
    const float* b_v    = (const float*)d_in[3];
    const float* b_h1   = (const float*)d_in[4];
    const float* W2     = (const float*)d_in[5];
    const float* b_h2   = (const float*)d_in[6];
    float* out = (float*)d_out;

    char* w = (char*)d_ws;
    short* vneg = (short*)w;                            // 5 x 8 MB fp16 states
    short* h1d  = vneg + (size_t)B_SZ * NV;
    short* h2d  = h1d  + (size_t)B_SZ * NH;
    short* h1c  = h2d  + (size_t)B_SZ * NH;
    short* h2n  = h1c  + (size_t)B_SZ * NH;
    float* P    = (float*)(h2n + (size_t)B_SZ * NH);    // 64 MB partials
    unsigned* cnt = (unsigned*)(P + (size_t)4 * 1024 * 4096);

    // d_out doubles as fp16 weight scratch (128 MB of the 134 MB output;
    // fully overwritten by gradient kernels afterwards).
    short* W1f = (short*)(((uintptr_t)(out + 1) + 15) & ~(uintptr_t)15);
    short* W1T = W1f + (size_t)NH * NV;
    short* W2f = W1T + (size_t)NH * NV;
    short* W2T = W2f + (size_t)NH * NH;

    // ---- JAX key derivation ----
    const uint32_t r0 = 0u, r1 = 42u;
    uint32_t kp1a, kp1b, kp2a, kp2b, kfa, kfb, kla, klb;
    tf2x32(r0, r1, 0u, 0u, kp1a, kp1b);
    tf2x32(r0, r1, 0u, 1u, kp2a, kp2b);
    tf2x32(r0, r1, 0u, 2u, kfa, kfb);
    tf2x32(r0, r1, 0u, 3u, kla, klb);
    uint32_t kaA[2], kaB[2], kbA[2], kbB[2], kcA[2], kcB[2];
    for (int i = 0; i < 2; ++i) {
        uint32_t fa, fb;
        tf2x32(kla, klb, 0u, (uint32_t)i, fa, fb);
        tf2x32(fa, fb, 0u, 0u, kaA[i], kaB[i]);
        tf2x32(fa, fb, 0u, 1u, kbA[i], kbB[i]);
        tf2x32(fa, fb, 0u, 2u, kcA[i], kcB[i]);
    }

    const int T = 256;
    const int NELEM = B_SZ * NH;
    dim3 gTr(64, 64);

    conv_tr<<<gTr, 256, 0, stream>>>(W1, W1f, W1T);
    conv_tr<<<gTr, 256, 0, stream>>>(W2, W2f, W2T);

    cvt_kernel<<<NELEM / T, T, 0, stream>>>(v_data, vneg, NELEM);

    // positive phase
    mm_chunk<0><<<512, 256, 0, stream>>>(vneg, nullptr, W1f, nullptr, P);
    combine_h<0, 2><<<2048, 256, 0, stream>>>(P, b_h1, h1d, nullptr, kp1a, kp1b);
    mm_chunk<0><<<512, 256, 0, stream>>>(h1d, nullptr, W2f, nullptr, P);
    combine_h<1, 2><<<2048, 256, 0, stream>>>(P, b_h2, h2d, h2n, kp2a, kp2b);

    // Gibbs loop (k = 2)
    for (int i = 0; i < 2; ++i) {
        mm_chunk<1><<<1024, 256, 0, stream>>>(vneg, h2n, W1f, W2T, P);
        combine_h<0, 4><<<2048, 256, 0, stream>>>(P, b_h1, h1c, nullptr, kaA[i], kaB[i]);
        mm_chunk<2><<<1024, 256, 0, stream>>>(h1c, nullptr, W2f, W1T, P);
        combine_dual<<<4096, 256, 0, stream>>>(P, b_h2, b_v, occ, h2n, vneg,
                                               kbA[i], kbB[i], kcA[i], kcB[i]);
    }

    // final hidden refresh
    mm_chunk<1><<<1024, 256, 0, stream>>>(vneg, h2n, W1f, W2T, P);
    combine_h<0, 4><<<2048, 256, 0, stream>>>(P, b_h1, h1c, nullptr, kfa, kfb);

    // outputs (weight scratch dead after this point)
    float* dW1o  = out + 1;
    float* dbvo  = dW1o + (size_t)NH * NV;
    float* dbh1o = dbvo + NV;
    float* dW2o  = dbh1o + NH;
    float* dbh2o = dW2o + (size_t)NH * NH;

    grad_mm<1><<<dim3(NSGN / 128, NH / 128), T, 0, stream>>>(h1c, vneg, h1d, (short*)nullptr, v_data, dW1o);
    grad_mm<0><<<dim3(NH / 128, NH / 128), T, 0, stream>>>(h1c, h2n, h1d, h2d, (const float*)nullptr, dW2o);
    dbv_fast<<<NSGN / 64, T, 0, stream>>>(v_data, vneg, dbvo);
    dbh_fast<<<NH / 64, T, 0, stream>>>(h1d, h1c, dbh1o);
    dbh_fast<<<NH / 64, T, 0, stream>>>(h2d, h2n, dbh2o);

    zero_kernel<<<1, 1, 0, stream>>>(cnt);
    loss_count2<<<1024, T, 0, stream>>>(v_data, vneg, cnt);
    loss_final_kernel<<<1, 1, 0, stream>>>(cnt, out, logf(1.0f + 1e-7f), logf(1e-7f));
}